// Round 1
// baseline (382.039 us; speedup 1.0000x reference)
//
#include <hip/hip_runtime.h>

// ---------------------------------------------------------------------------
// GAT encoder, 2 layers, H=4 heads, fp32 throughout.
// Structure exploited: dst[e] = e % N  =>  node v's 16 incoming edges are
// e = v + k*N, k=0..15. Edge softmax therefore reduces to a 16-lane shuffle
// reduction; aggregation is a gather of 16 random 1KB rows per node.
// ---------------------------------------------------------------------------

#define NNODES 50000

// ---------------------------------------------------------------------------
// GEMM + attention-coefficient epilogue.
//   C[v, colOff + c] = sum_k X[v,k] * W[k, colOff + c]        (c in [0,64*CPL))
//   el[v,h] = sum_c C[v,c]*al[c],  er[v,h] = sum_c C[v,c]*ar[c]  (per head)
// One wave computes 8 rows; lane covers CPL consecutive columns.
// W slice staged in LDS (64 KiB); X row elements are wave-uniform -> s_load.
// ---------------------------------------------------------------------------
template <int F, int CPL>
__global__ __launch_bounds__(256) void gemm_att_kernel(
    const float* __restrict__ X, const float* __restrict__ W,
    const float* __restrict__ al, const float* __restrict__ ar,
    float* __restrict__ C, float* __restrict__ el, float* __restrict__ er,
    int N) {
  constexpr int CB = 64 * CPL;  // columns per block
  __shared__ float Wl[F * CB];  // 64 KiB for both instantiations

  const int tid = threadIdx.x;
  const int colOff = blockIdx.y * CB;

  // Stage W slice: 16384 floats, 256 threads x 16 float4s, coalesced.
  for (int idx = tid * 4; idx < F * CB; idx += 1024) {
    const int kk = idx / CB;
    const int cc = idx - kk * CB;
    *reinterpret_cast<float4*>(&Wl[idx]) =
        *reinterpret_cast<const float4*>(W + kk * 256 + colOff + cc);
  }
  __syncthreads();

  const int lane = tid & 63;
  const int wv = __builtin_amdgcn_readfirstlane(tid >> 6);  // force uniform

  float alv[CPL], arv[CPL];
#pragma unroll
  for (int j = 0; j < CPL; ++j) {
    alv[j] = al[colOff + lane * CPL + j];
    arv[j] = ar[colOff + lane * CPL + j];
  }

  const int nChunks = (N + 31) >> 5;  // 32 rows per block-iteration
  for (int ch = blockIdx.x; ch < nChunks; ch += gridDim.x) {
    const int row0 = ch * 32 + wv * 8;

    float acc[8][CPL];
#pragma unroll
    for (int r = 0; r < 8; ++r)
#pragma unroll
      for (int j = 0; j < CPL; ++j) acc[r][j] = 0.0f;

    const float* xr[8];
#pragma unroll
    for (int r = 0; r < 8; ++r) {
      int rr = row0 + r;
      if (rr > N - 1) rr = N - 1;  // clamp (stores are guarded below)
      xr[r] = X + (size_t)rr * F;  // wave-uniform pointer -> scalar loads
    }

#pragma unroll 16
    for (int k = 0; k < F; ++k) {
      float wl[CPL];
      if constexpr (CPL == 2) {
        float2 t = *reinterpret_cast<const float2*>(&Wl[k * CB + lane * 2]);
        wl[0] = t.x;
        wl[1] = t.y;
      } else {
        float4 t = *reinterpret_cast<const float4*>(&Wl[k * CB + lane * 4]);
        wl[0] = t.x;
        wl[1] = t.y;
        wl[2] = t.z;
        wl[3] = t.w;
      }
#pragma unroll
      for (int r = 0; r < 8; ++r) {
        const float a = xr[r][k];  // uniform -> SGPR operand of v_fmac
#pragma unroll
        for (int j = 0; j < CPL; ++j) acc[r][j] = fmaf(a, wl[j], acc[r][j]);
      }
    }

    // Epilogue: store C slice + per-head attention dots.
    constexpr int G = 64 / CPL;  // lanes per head (head = 64 columns)
#pragma unroll
    for (int r = 0; r < 8; ++r) {
      const int row = row0 + r;
      if (row < N) {
        if constexpr (CPL == 2) {
          float2 o;
          o.x = acc[r][0];
          o.y = acc[r][1];
          *reinterpret_cast<float2*>(C + (size_t)row * 256 + colOff + lane * 2) = o;
        } else {
          float4 o;
          o.x = acc[r][0];
          o.y = acc[r][1];
          o.z = acc[r][2];
          o.w = acc[r][3];
          *reinterpret_cast<float4*>(C + (size_t)row * 256 + colOff + lane * 4) = o;
        }
        float pl = 0.0f, pr = 0.0f;
#pragma unroll
        for (int j = 0; j < CPL; ++j) {
          pl = fmaf(acc[r][j], alv[j], pl);
          pr = fmaf(acc[r][j], arv[j], pr);
        }
#pragma unroll
        for (int d = 1; d < G; d <<= 1) {
          pl += __shfl_xor(pl, d, G);
          pr += __shfl_xor(pr, d, G);
        }
        if ((lane & (G - 1)) == 0) {
          const int hh = colOff / 64 + lane / G;
          el[(size_t)row * 4 + hh] = pl;
          er[(size_t)row * 4 + hh] = pr;
        }
      }
    }
  }
}

// ---------------------------------------------------------------------------
// Per-node edge softmax + aggregation + head-mean.
// One wave per node. Lane l: edge k = l&15, head h = l>>4 (attention phase);
// gather phase: lane l accumulates output columns 4l..4l+3 (head l>>4).
// ---------------------------------------------------------------------------
__global__ __launch_bounds__(256) void agg_kernel(
    const float* __restrict__ C, const float* __restrict__ el,
    const float* __restrict__ er, const float* __restrict__ b,
    const int* __restrict__ src, float* __restrict__ out, int N) {
  const int lane = threadIdx.x & 63;
  const int wv = threadIdx.x >> 6;
  const int node = blockIdx.x * 4 + wv;
  if (node >= N) return;  // wave-uniform

  const int k = lane & 15;
  const int h = lane >> 4;

  const int s = src[node + k * N];  // edge e = node + k*N has dst == node
  float e = el[(size_t)s * 4 + h] + er[(size_t)node * 4 + h];
  e = (e > 0.0f) ? e : 0.2f * e;  // leaky_relu slope 0.2

  // softmax over the 16 edges, within each 16-lane head group
  float m = e;
#pragma unroll
  for (int d = 1; d < 16; d <<= 1) m = fmaxf(m, __shfl_xor(m, d, 16));
  const float ex = __expf(e - m);
  float den = ex;
#pragma unroll
  for (int d = 1; d < 16; d <<= 1) den += __shfl_xor(den, d, 16);
  const float alpha = ex / den;

  // gather + weighted accumulate: 16 rows of 256 floats (1 KiB coalesced each)
  float a0 = 0.f, a1 = 0.f, a2 = 0.f, a3 = 0.f;
#pragma unroll
  for (int kk = 0; kk < 16; ++kk) {
    const int sk = __shfl(s, kk, 16);
    const float av = __shfl(alpha, kk, 16);
    const float4 v =
        *reinterpret_cast<const float4*>(C + (size_t)sk * 256 + lane * 4);
    a0 = fmaf(av, v.x, a0);
    a1 = fmaf(av, v.y, a1);
    a2 = fmaf(av, v.z, a2);
    a3 = fmaf(av, v.w, a3);
  }

  // head mean: sum lanes l, l^16, l^32, l^48 then scale by 1/4
  a0 += __shfl_xor(a0, 16);
  a1 += __shfl_xor(a1, 16);
  a2 += __shfl_xor(a2, 16);
  a3 += __shfl_xor(a3, 16);
  a0 += __shfl_xor(a0, 32);
  a1 += __shfl_xor(a1, 32);
  a2 += __shfl_xor(a2, 32);
  a3 += __shfl_xor(a3, 32);

  if (lane < 16) {
    const int c = lane * 4;
    float4 o;
    o.x = 0.25f * (a0 + b[c + 0] + b[64 + c + 0] + b[128 + c + 0] + b[192 + c + 0]);
    o.y = 0.25f * (a1 + b[c + 1] + b[64 + c + 1] + b[128 + c + 1] + b[192 + c + 1]);
    o.z = 0.25f * (a2 + b[c + 2] + b[64 + c + 2] + b[128 + c + 2] + b[192 + c + 2]);
    o.w = 0.25f * (a3 + b[c + 3] + b[64 + c + 3] + b[128 + c + 3] + b[192 + c + 3]);
    *reinterpret_cast<float4*>(out + (size_t)node * 64 + c) = o;
  }
}

// ---------------------------------------------------------------------------
extern "C" void kernel_launch(void* const* d_in, const int* in_sizes, int n_in,
                              void* d_out, int out_size, void* d_ws,
                              size_t ws_size, hipStream_t stream) {
  const float* feat = (const float*)d_in[0];
  const int* src = (const int*)d_in[1];
  // d_in[2] = dst: structurally dst[e] = e % N (arange % N) -> not needed.
  const float* W1 = (const float*)d_in[3];
  const float* al1 = (const float*)d_in[4];
  const float* ar1 = (const float*)d_in[5];
  const float* b1 = (const float*)d_in[6];
  const float* W2 = (const float*)d_in[7];
  const float* al2 = (const float*)d_in[8];
  const float* ar2 = (const float*)d_in[9];
  const float* b2 = (const float*)d_in[10];
  float* out = (float*)d_out;

  const int N = NNODES;

  // Workspace: C (N*256) | el (N*4) | er (N*4)  = 52.8 MB
  float* C = (float*)d_ws;
  float* el = C + (size_t)N * 256;
  float* er = el + (size_t)N * 4;
  // x2 (layer-1 output, N*64) lives in d_out: fully written by agg #1 before
  // gemm #2 reads it, fully overwritten by agg #2. Deterministic.
  float* x2 = out;

  const dim3 blk(256);

  // Layer 1
  gemm_att_kernel<128, 2>
      <<<dim3(256, 2), blk, 0, stream>>>(feat, W1, al1, ar1, C, el, er, N);
  agg_kernel<<<dim3((N + 3) / 4), blk, 0, stream>>>(C, el, er, b1, src, x2, N);

  // Layer 2
  gemm_att_kernel<64, 4>
      <<<dim3(512, 1), blk, 0, stream>>>(x2, W2, al2, ar2, C, el, er, N);
  agg_kernel<<<dim3((N + 3) / 4), blk, 0, stream>>>(C, el, er, b2, src, out, N);
}

// Round 2
// 378.106 us; speedup vs baseline: 1.0104x; 1.0104x over previous
//
#include <hip/hip_runtime.h>

// ---------------------------------------------------------------------------
// GAT encoder, 2 layers, H=4 heads, fp32 throughout.
// dst[e] = e % N  =>  node v's 16 incoming edges are e = v + k*N.
// ---------------------------------------------------------------------------

#define NNODES 50000

// ---------------------------------------------------------------------------
// GEMM + attention-coefficient epilogue, v2 (row-per-lane).
//   C[v, head*64 + c] = sum_k X[v,k] * W[k, head*64+c]
//   el[v,head] = sum_c C[v,head*64+c]*al[head,c]   (same for er/ar)
// Block = 256 threads = 4 waves; each lane owns ONE row and all 64 columns
// of ONE head (acc[64] in VGPRs). W slice (F x 64) staged in LDS, read with
// wave-uniform (broadcast, conflict-free) ds_read_b128. X read per-lane as
// float4 (each row fully consumed -> full cacheline utilization via L1/L2).
// ---------------------------------------------------------------------------
template <int F>
__global__ __launch_bounds__(256) void gemm_att_v2(
    const float* __restrict__ X, const float* __restrict__ W,
    const float* __restrict__ al, const float* __restrict__ ar,
    float* __restrict__ C, float* __restrict__ el, float* __restrict__ er,
    int N) {
  __shared__ float Wl[F * 64];  // 32 KiB (F=128) / 16 KiB (F=64)

  const int tid = threadIdx.x;
  const int head = blockIdx.y;  // one head = 64 columns
  const int colOff = head * 64;

  // Stage W slice: F*64 floats, coalesced float4.
  for (int idx = tid * 4; idx < F * 64; idx += 1024) {
    const int kk = idx >> 6;
    const int cc = idx & 63;
    *reinterpret_cast<float4*>(&Wl[idx]) =
        *reinterpret_cast<const float4*>(W + kk * 256 + colOff + cc);
  }
  __syncthreads();

  const int lane = tid & 63;
  const int wv = tid >> 6;
  int row = blockIdx.x * 256 + wv * 64 + lane;
  const bool valid = (row < N);
  if (!valid) row = N - 1;  // clamp loads; stores guarded below

  const float* __restrict__ xr = X + (size_t)row * F;

  float acc[64];
#pragma unroll
  for (int c = 0; c < 64; ++c) acc[c] = 0.0f;

  for (int k = 0; k < F; k += 4) {
    const float4 x4 = *reinterpret_cast<const float4*>(xr + k);
    float xs[4] = {x4.x, x4.y, x4.z, x4.w};
#pragma unroll
    for (int kk = 0; kk < 4; ++kk) {
      const float xv = xs[kk];
#pragma unroll
      for (int c = 0; c < 64; ++c)
        acc[c] = fmaf(xv, Wl[(k + kk) * 64 + c], acc[c]);
    }
  }

  // Attention dots: lane owns the whole head -> pure per-lane reduction.
  float pl = 0.0f, pr = 0.0f;
#pragma unroll
  for (int c = 0; c < 64; ++c) {
    pl = fmaf(acc[c], al[colOff + c], pl);  // uniform -> scalar loads
    pr = fmaf(acc[c], ar[colOff + c], pr);
  }

  if (valid) {
    el[(size_t)row * 4 + head] = pl;
    er[(size_t)row * 4 + head] = pr;
#pragma unroll
    for (int c = 0; c < 64; c += 4) {
      float4 o;
      o.x = acc[c + 0];
      o.y = acc[c + 1];
      o.z = acc[c + 2];
      o.w = acc[c + 3];
      *reinterpret_cast<float4*>(C + (size_t)row * 256 + colOff + c) = o;
    }
  }
}

// ---------------------------------------------------------------------------
// Per-node edge softmax + aggregation + head-mean.
// One wave per node. Lane l: edge k = l&15, head h = l>>4 (attention phase);
// gather phase: lane l accumulates output columns 4l..4l+3.
// ---------------------------------------------------------------------------
__global__ __launch_bounds__(256) void agg_kernel(
    const float* __restrict__ C, const float* __restrict__ el,
    const float* __restrict__ er, const float* __restrict__ b,
    const int* __restrict__ src, float* __restrict__ out, int N) {
  const int lane = threadIdx.x & 63;
  const int wv = threadIdx.x >> 6;
  const int node = blockIdx.x * 4 + wv;
  if (node >= N) return;  // wave-uniform

  const int k = lane & 15;
  const int h = lane >> 4;

  const int s = src[node + k * N];  // edge e = node + k*N has dst == node
  float e = el[(size_t)s * 4 + h] + er[(size_t)node * 4 + h];
  e = (e > 0.0f) ? e : 0.2f * e;  // leaky_relu slope 0.2

  // softmax over the 16 edges, within each 16-lane head group
  float m = e;
#pragma unroll
  for (int d = 1; d < 16; d <<= 1) m = fmaxf(m, __shfl_xor(m, d, 16));
  const float ex = __expf(e - m);
  float den = ex;
#pragma unroll
  for (int d = 1; d < 16; d <<= 1) den += __shfl_xor(den, d, 16);
  const float alpha = ex / den;

  // gather + weighted accumulate: 16 rows of 1 KiB, coalesced float4
  float a0 = 0.f, a1 = 0.f, a2 = 0.f, a3 = 0.f;
#pragma unroll
  for (int kk = 0; kk < 16; ++kk) {
    const int sk = __shfl(s, kk, 16);
    const float av = __shfl(alpha, kk, 16);
    const float4 v =
        *reinterpret_cast<const float4*>(C + (size_t)sk * 256 + lane * 4);
    a0 = fmaf(av, v.x, a0);
    a1 = fmaf(av, v.y, a1);
    a2 = fmaf(av, v.z, a2);
    a3 = fmaf(av, v.w, a3);
  }

  // head mean: sum lanes l, l^16, l^32, l^48 then scale by 1/4
  a0 += __shfl_xor(a0, 16);
  a1 += __shfl_xor(a1, 16);
  a2 += __shfl_xor(a2, 16);
  a3 += __shfl_xor(a3, 16);
  a0 += __shfl_xor(a0, 32);
  a1 += __shfl_xor(a1, 32);
  a2 += __shfl_xor(a2, 32);
  a3 += __shfl_xor(a3, 32);

  if (lane < 16) {
    const int c = lane * 4;
    float4 o;
    o.x = 0.25f * (a0 + b[c + 0] + b[64 + c + 0] + b[128 + c + 0] + b[192 + c + 0]);
    o.y = 0.25f * (a1 + b[c + 1] + b[64 + c + 1] + b[128 + c + 1] + b[192 + c + 1]);
    o.z = 0.25f * (a2 + b[c + 2] + b[64 + c + 2] + b[128 + c + 2] + b[192 + c + 2]);
    o.w = 0.25f * (a3 + b[c + 3] + b[64 + c + 3] + b[128 + c + 3] + b[192 + c + 3]);
    *reinterpret_cast<float4*>(out + (size_t)node * 64 + c) = o;
  }
}

// ---------------------------------------------------------------------------
extern "C" void kernel_launch(void* const* d_in, const int* in_sizes, int n_in,
                              void* d_out, int out_size, void* d_ws,
                              size_t ws_size, hipStream_t stream) {
  const float* feat = (const float*)d_in[0];
  const int* src = (const int*)d_in[1];
  // d_in[2] = dst: structurally dst[e] = e % N -> not needed.
  const float* W1 = (const float*)d_in[3];
  const float* al1 = (const float*)d_in[4];
  const float* ar1 = (const float*)d_in[5];
  const float* b1 = (const float*)d_in[6];
  const float* W2 = (const float*)d_in[7];
  const float* al2 = (const float*)d_in[8];
  const float* ar2 = (const float*)d_in[9];
  const float* b2 = (const float*)d_in[10];
  float* out = (float*)d_out;

  const int N = NNODES;

  // Workspace: C (N*256) | el (N*4) | er (N*4)  = 52.8 MB
  float* C = (float*)d_ws;
  float* el = C + (size_t)N * 256;
  float* er = el + (size_t)N * 4;
  // x2 (layer-1 output, N*64) staged in d_out: fully written by agg #1 before
  // gemm #2 reads it, fully overwritten by agg #2. Deterministic.
  float* x2 = out;

  const dim3 blk(256);
  const int rowBlocks = (N + 255) / 256;

  // Layer 1
  gemm_att_v2<128>
      <<<dim3(rowBlocks, 4), blk, 0, stream>>>(feat, W1, al1, ar1, C, el, er, N);
  agg_kernel<<<dim3((N + 3) / 4), blk, 0, stream>>>(C, el, er, b1, src, x2, N);

  // Layer 2
  gemm_att_v2<64>
      <<<dim3(rowBlocks, 4), blk, 0, stream>>>(x2, W2, al2, ar2, C, el, er, N);
  agg_kernel<<<dim3((N + 3) / 4), blk, 0, stream>>>(C, el, er, b2, src, out, N);
}

// Round 3
// 241.733 us; speedup vs baseline: 1.5804x; 1.5641x over previous
//
#include <hip/hip_runtime.h>

// ---------------------------------------------------------------------------
// GAT encoder, 2 layers, H=4 heads, fp32.
// dst[e] = e % N  =>  node v's 16 incoming edges are e = v + k*N.
// Key restructure: aggregation commutes with projection (linearity):
//   out[v] = (1/H) sum_h (sum_k alpha[v,k,h] * x[src_k]) @ W_h  + mean_h(b_h)
//   el[v,h] = x[v] . (W_h @ al_h)   (precomputed F-vector per head)
// So we gather RAW x rows (512B / 256B) instead of projected rows (1KB),
// and never materialize h = x@W. Gather traffic: 1.6GB -> 600MB.
// ---------------------------------------------------------------------------

#define NNODES 50000

// ---------------- prep: wal/war[k*4+h] = sum_c W[k,h*64+c]*a[h,c]; bavg ------
__global__ void prep_kernel(const float* __restrict__ W1, const float* __restrict__ al1,
                            const float* __restrict__ ar1, const float* __restrict__ b1,
                            const float* __restrict__ W2, const float* __restrict__ al2,
                            const float* __restrict__ ar2, const float* __restrict__ b2,
                            float* __restrict__ P) {
  const int t = blockIdx.x * 256 + threadIdx.x;
  if (t < 512) {  // wal1
    const int k = t >> 2, h = t & 3;
    float s = 0.f;
    for (int c = 0; c < 64; ++c) s = fmaf(W1[k * 256 + h * 64 + c], al1[h * 64 + c], s);
    P[t] = s;
  } else if (t < 1024) {  // war1
    const int u = t - 512, k = u >> 2, h = u & 3;
    float s = 0.f;
    for (int c = 0; c < 64; ++c) s = fmaf(W1[k * 256 + h * 64 + c], ar1[h * 64 + c], s);
    P[t] = s;
  } else if (t < 1280) {  // wal2
    const int u = t - 1024, k = u >> 2, h = u & 3;
    float s = 0.f;
    for (int c = 0; c < 64; ++c) s = fmaf(W2[k * 256 + h * 64 + c], al2[h * 64 + c], s);
    P[t] = s;
  } else if (t < 1536) {  // war2
    const int u = t - 1280, k = u >> 2, h = u & 3;
    float s = 0.f;
    for (int c = 0; c < 64; ++c) s = fmaf(W2[k * 256 + h * 64 + c], ar2[h * 64 + c], s);
    P[t] = s;
  } else if (t < 1600) {  // bavg1
    const int c = t - 1536;
    P[t] = 0.25f * (b1[c] + b1[64 + c] + b1[128 + c] + b1[192 + c]);
  } else if (t < 1664) {  // bavg2
    const int c = t - 1600;
    P[t] = 0.25f * (b2[c] + b2[64 + c] + b2[128 + c] + b2[192 + c]);
  }
}

// ---------------- attcoef: el[v,h] = x[v] . wal[:,h] ------------------------
template <int F>
__global__ __launch_bounds__(256) void attcoef_kernel(
    const float* __restrict__ X, const float* __restrict__ wal,
    const float* __restrict__ war, float* __restrict__ el, float* __restrict__ er,
    int N) {
  __shared__ float4 WL[F], WR[F];  // [k] -> (h0..h3)
  const int tid = threadIdx.x;
  for (int i = tid; i < F; i += 256) {
    WL[i] = reinterpret_cast<const float4*>(wal)[i];
    WR[i] = reinterpret_cast<const float4*>(war)[i];
  }
  __syncthreads();
  const int row = blockIdx.x * 256 + tid;
  if (row >= N) return;
  const float* __restrict__ xr = X + (size_t)row * F;
  float accl[4] = {0, 0, 0, 0}, accr[4] = {0, 0, 0, 0};
  for (int k = 0; k < F; k += 4) {
    const float4 x4 = *reinterpret_cast<const float4*>(xr + k);
    const float xs[4] = {x4.x, x4.y, x4.z, x4.w};
#pragma unroll
    for (int kk = 0; kk < 4; ++kk) {
      const float4 wl = WL[k + kk], wr = WR[k + kk];
      accl[0] = fmaf(xs[kk], wl.x, accl[0]);
      accl[1] = fmaf(xs[kk], wl.y, accl[1]);
      accl[2] = fmaf(xs[kk], wl.z, accl[2]);
      accl[3] = fmaf(xs[kk], wl.w, accl[3]);
      accr[0] = fmaf(xs[kk], wr.x, accr[0]);
      accr[1] = fmaf(xs[kk], wr.y, accr[1]);
      accr[2] = fmaf(xs[kk], wr.z, accr[2]);
      accr[3] = fmaf(xs[kk], wr.w, accr[3]);
    }
  }
  float4 o;
  o.x = accl[0]; o.y = accl[1]; o.z = accl[2]; o.w = accl[3];
  *reinterpret_cast<float4*>(el + (size_t)row * 4) = o;
  o.x = accr[0]; o.y = accr[1]; o.z = accr[2]; o.w = accr[3];
  *reinterpret_cast<float4*>(er + (size_t)row * 4) = o;
}

// ---------------- agg: softmax + gather x rows -> g[v,h,:] ------------------
// wave per node; lanes (k = lane&15, h = lane>>4) for softmax;
// gather: lane covers feature slice for all 4 heads.
template <int F>
__global__ __launch_bounds__(256) void agg_kernel2(
    const float* __restrict__ X, const float* __restrict__ el,
    const float* __restrict__ er, const int* __restrict__ src,
    float* __restrict__ g, int node0, int node1, int N) {
  const int lane = threadIdx.x & 63;
  const int wv = threadIdx.x >> 6;
  const int node = node0 + blockIdx.x * 4 + wv;
  if (node >= node1) return;

  const int k = lane & 15;
  const int h = lane >> 4;
  const int s = src[node + k * N];
  float e = el[(size_t)s * 4 + h] + er[(size_t)node * 4 + h];
  e = (e > 0.0f) ? e : 0.2f * e;  // leaky_relu 0.2
  float m = e;
#pragma unroll
  for (int d = 1; d < 16; d <<= 1) m = fmaxf(m, __shfl_xor(m, d, 16));
  const float ex = __expf(e - m);
  float den = ex;
#pragma unroll
  for (int d = 1; d < 16; d <<= 1) den += __shfl_xor(den, d, 16);
  const float alpha = ex / den;

  const size_t gbase = (size_t)(node - node0) * (4 * F);

  if constexpr (F == 128) {
    float2 a0{0, 0}, a1{0, 0}, a2{0, 0}, a3{0, 0};
#pragma unroll
    for (int kk = 0; kk < 16; ++kk) {
      const int sk = __shfl(s, kk, 16);
      const float v0 = __shfl(alpha, kk, 64);
      const float v1 = __shfl(alpha, kk + 16, 64);
      const float v2 = __shfl(alpha, kk + 32, 64);
      const float v3 = __shfl(alpha, kk + 48, 64);
      const float2 x = *reinterpret_cast<const float2*>(X + (size_t)sk * 128 + lane * 2);
      a0.x = fmaf(v0, x.x, a0.x); a0.y = fmaf(v0, x.y, a0.y);
      a1.x = fmaf(v1, x.x, a1.x); a1.y = fmaf(v1, x.y, a1.y);
      a2.x = fmaf(v2, x.x, a2.x); a2.y = fmaf(v2, x.y, a2.y);
      a3.x = fmaf(v3, x.x, a3.x); a3.y = fmaf(v3, x.y, a3.y);
    }
    *reinterpret_cast<float2*>(g + gbase + 0 * 128 + lane * 2) = a0;
    *reinterpret_cast<float2*>(g + gbase + 1 * 128 + lane * 2) = a1;
    *reinterpret_cast<float2*>(g + gbase + 2 * 128 + lane * 2) = a2;
    *reinterpret_cast<float2*>(g + gbase + 3 * 128 + lane * 2) = a3;
  } else {
    float a0 = 0, a1 = 0, a2 = 0, a3 = 0;
#pragma unroll
    for (int kk = 0; kk < 16; ++kk) {
      const int sk = __shfl(s, kk, 16);
      const float v0 = __shfl(alpha, kk, 64);
      const float v1 = __shfl(alpha, kk + 16, 64);
      const float v2 = __shfl(alpha, kk + 32, 64);
      const float v3 = __shfl(alpha, kk + 48, 64);
      const float x = X[(size_t)sk * 64 + lane];
      a0 = fmaf(v0, x, a0);
      a1 = fmaf(v1, x, a1);
      a2 = fmaf(v2, x, a2);
      a3 = fmaf(v3, x, a3);
    }
    g[gbase + 0 * 64 + lane] = a0;
    g[gbase + 1 * 64 + lane] = a1;
    g[gbase + 2 * 64 + lane] = a2;
    g[gbase + 3 * 64 + lane] = a3;
  }
}

// ---------------- dgemm: out[v,c] = 0.25*sum_{h,j} g[v,h,j] W[j,h*64+c] + bavg
// Block: 128 rows x 64 cols, 4 waves (2r x 2c), lane tile 8x4.
// Xt staged TRANSPOSED in LDS (b128 row-reads, conflict-free); W tile staged
// k-major. Global loads reg-staged before barrier to overlap prior compute.
template <int K>  // 512 (layer1) or 256 (layer2)
__global__ __launch_bounds__(256) void dgemm_kernel(
    const float* __restrict__ g, const float* __restrict__ W,
    const float* __restrict__ bavg, float* __restrict__ out,
    int node0, int nrows) {
  constexpr int F = K / 4;
  constexpr int KT = 32;
  constexpr int XS = 132;        // 128 rows + 4 pad words (16B-aligned rows)
  __shared__ float Xt[KT * XS];  // 16.9 KB
  __shared__ float Wt[KT * 64];  // 8 KB

  const int tid = threadIdx.x;
  const int row0 = blockIdx.x * 128;
  const int lane = tid & 63;
  const int wv = tid >> 6;
  const int wrow = wv >> 1;
  const int wcol = wv & 1;
  const int rr = lane >> 3;
  const int cc = lane & 7;
  const int xoff = wrow * 64 + rr * 8;
  const int woff = wcol * 32 + cc * 4;

  float acc[8][4];
#pragma unroll
  for (int i = 0; i < 8; ++i)
#pragma unroll
    for (int j = 0; j < 4; ++j) acc[i][j] = 0.0f;

  const int sr = tid >> 3;  // staging row 0..31
  const int sm = tid & 7;   // staging k-float4

  for (int k0 = 0; k0 < K; k0 += KT) {
    // reg-stage global loads (issue before barrier -> overlap prev compute)
    float4 gx[4];
#pragma unroll
    for (int p = 0; p < 4; ++p) {
      const int gr = row0 + sr + p * 32;
      if (gr < nrows)
        gx[p] = *reinterpret_cast<const float4*>(g + (size_t)gr * K + k0 + sm * 4);
      else
        gx[p] = float4{0.f, 0.f, 0.f, 0.f};
    }
    float4 gw[2];
#pragma unroll
    for (int p = 0; p < 2; ++p) {
      const int kk = (tid >> 4) + p * 16;
      const int kg = k0 + kk;
      const int h = kg / F;
      const int j = kg & (F - 1);
      gw[p] = *reinterpret_cast<const float4*>(W + (size_t)j * 256 + h * 64 + (tid & 15) * 4);
    }
    __syncthreads();  // prev-iter readers done
#pragma unroll
    for (int p = 0; p < 4; ++p) {
      const int r = sr + p * 32;
      Xt[(sm * 4 + 0) * XS + r] = gx[p].x;
      Xt[(sm * 4 + 1) * XS + r] = gx[p].y;
      Xt[(sm * 4 + 2) * XS + r] = gx[p].z;
      Xt[(sm * 4 + 3) * XS + r] = gx[p].w;
    }
#pragma unroll
    for (int p = 0; p < 2; ++p) {
      const int kk = (tid >> 4) + p * 16;
      *reinterpret_cast<float4*>(&Wt[kk * 64 + (tid & 15) * 4]) = gw[p];
    }
    __syncthreads();

    float4 xa = *reinterpret_cast<const float4*>(&Xt[xoff]);
    float4 xb = *reinterpret_cast<const float4*>(&Xt[xoff + 4]);
    float4 wa = *reinterpret_cast<const float4*>(&Wt[woff]);
#pragma unroll
    for (int kk = 0; kk < KT; ++kk) {
      float4 nxa = xa, nxb = xb, nwa = wa;
      if (kk + 1 < KT) {
        nxa = *reinterpret_cast<const float4*>(&Xt[(kk + 1) * XS + xoff]);
        nxb = *reinterpret_cast<const float4*>(&Xt[(kk + 1) * XS + xoff + 4]);
        nwa = *reinterpret_cast<const float4*>(&Wt[(kk + 1) * 64 + woff]);
      }
      const float xs[8] = {xa.x, xa.y, xa.z, xa.w, xb.x, xb.y, xb.z, xb.w};
      const float wv4[4] = {wa.x, wa.y, wa.z, wa.w};
#pragma unroll
      for (int i = 0; i < 8; ++i)
#pragma unroll
        for (int j = 0; j < 4; ++j) acc[i][j] = fmaf(xs[i], wv4[j], acc[i][j]);
      xa = nxa; xb = nxb; wa = nwa;
    }
  }

  const float4 bv = *reinterpret_cast<const float4*>(bavg + woff);
#pragma unroll
  for (int i = 0; i < 8; ++i) {
    const int lr = row0 + wrow * 64 + rr * 8 + i;
    if (lr < nrows) {
      float4 o;
      o.x = 0.25f * acc[i][0] + bv.x;
      o.y = 0.25f * acc[i][1] + bv.y;
      o.z = 0.25f * acc[i][2] + bv.z;
      o.w = 0.25f * acc[i][3] + bv.w;
      *reinterpret_cast<float4*>(out + (size_t)(node0 + lr) * 64 + woff) = o;
    }
  }
}

// ---------------------------------------------------------------------------
extern "C" void kernel_launch(void* const* d_in, const int* in_sizes, int n_in,
                              void* d_out, int out_size, void* d_ws,
                              size_t ws_size, hipStream_t stream) {
  const float* feat = (const float*)d_in[0];
  const int* src = (const int*)d_in[1];
  // d_in[2] = dst: structurally dst[e] = e % N -> not needed.
  const float* W1 = (const float*)d_in[3];
  const float* al1 = (const float*)d_in[4];
  const float* ar1 = (const float*)d_in[5];
  const float* b1 = (const float*)d_in[6];
  const float* W2 = (const float*)d_in[7];
  const float* al2 = (const float*)d_in[8];
  const float* ar2 = (const float*)d_in[9];
  const float* b2 = (const float*)d_in[10];
  float* out = (float*)d_out;

  const int N = NNODES;

  // Pick layer-1 chunk count so g fits ws (R1 proved ws >= 52.8MB -> nc1<=4 fits).
  const size_t ws_elems = ws_size / 4;
  int nc1 = 1, csz1 = 0;
  for (; nc1 <= 16; nc1 <<= 1) {
    csz1 = (((N + nc1 - 1) / nc1) + 255) & ~255;
    const size_t need = (size_t)csz1 * 512 + (size_t)N * 64 + (size_t)N * 8 + 1664;
    if (need <= ws_elems) break;
  }

  float* g = (float*)d_ws;                    // csz1*512 floats
  float* x2 = g + (size_t)csz1 * 512;         // N*64
  float* el = x2 + (size_t)N * 64;            // N*4
  float* er = el + (size_t)N * 4;             // N*4
  float* P = er + (size_t)N * 4;              // params: 1664 floats
  float* wal1 = P;
  float* war1 = P + 512;
  float* wal2 = P + 1024;
  float* war2 = P + 1280;
  float* bavg1 = P + 1536;
  float* bavg2 = P + 1600;

  prep_kernel<<<7, 256, 0, stream>>>(W1, al1, ar1, b1, W2, al2, ar2, b2, P);

  // ---- Layer 1 ----
  attcoef_kernel<128><<<(N + 255) / 256, 256, 0, stream>>>(feat, wal1, war1, el, er, N);
  for (int c = 0; c < nc1; ++c) {
    const int n0 = c * csz1;
    if (n0 >= N) break;
    const int n1 = (n0 + csz1 < N) ? n0 + csz1 : N;
    agg_kernel2<128><<<(n1 - n0 + 3) / 4, 256, 0, stream>>>(feat, el, er, src, g, n0, n1, N);
    dgemm_kernel<512><<<(n1 - n0 + 127) / 128, 256, 0, stream>>>(g, W1, bavg1, x2, n0, n1 - n0);
  }

  // ---- Layer 2 ---- (g capacity allows bigger chunks: K halves)
  const size_t cap = (size_t)csz1 * 512;
  int csz2 = (int)((cap / 256) & ~(size_t)255);
  const int nAligned = (N + 255) & ~255;
  if (csz2 > nAligned) csz2 = nAligned;
  attcoef_kernel<64><<<(N + 255) / 256, 256, 0, stream>>>(x2, wal2, war2, el, er, N);
  for (int n0 = 0; n0 < N; n0 += csz2) {
    const int n1 = (n0 + csz2 < N) ? n0 + csz2 : N;
    agg_kernel2<64><<<(n1 - n0 + 3) / 4, 256, 0, stream>>>(x2, el, er, src, g, n0, n1, N);
    dgemm_kernel<256><<<(n1 - n0 + 127) / 128, 256, 0, stream>>>(g, W2, bavg2, out, n0, n1 - n0);
  }
}